// Round 4
// baseline (32.271 us; speedup 1.0000x reference)
//
#include <hip/hip_runtime.h>
#include <math.h>

#define NSZ 512
#define MSZ 256
#define NPIX (6 * NSZ * NSZ)                      // 1,572,864 vertices
#define NQ   ((NSZ - 1) * (NSZ - 1))              // 261,121 quads per cube face
#define NFACE (6 * 2 * NQ)                        // 3,133,452 triangles
#define F3TOT (NFACE * 3)                         // 9,400,356 floats (divisible by 12)
#define TS 32                                     // output tile
#define HS (TS + 2)                               // vert halo = 34
#define PS 20                                     // input patch = 20x20 texels
#define NVB (6 * 16 * 16)                         // 1536 vert/normal blocks
#define NFT12 (F3TOT / 12)                        // 783,363 faces threads (12 floats each)
#define GRID (NVB * 3)                            // 4608 blocks: [vert, faces, faces] triples

// ---- fast math helpers (raw HW op + 1 Newton step, rel err ~1e-7) --------
__device__ inline float fast_rcp(float x) {
    float r = __builtin_amdgcn_rcpf(x);
    return r * (2.0f - x * r);
}
__device__ inline float fast_rsqrt(float d) {       // d > 0
    float r = __builtin_amdgcn_rsqf(d);
    return r * (1.5f - 0.5f * d * r * r);
}
__device__ inline float fast_sigmoid(float x) {
    float e = __builtin_amdgcn_exp2f(-1.442695040888963f * x);
    return fast_rcp(1.0f + e);
}

// triangle unit-normal accumulate; degenerate (duplicated corner) tris give an
// exactly-zero cross product -> contribute exactly 0 (no masking needed).
__device__ inline void tri_acc4(const float4 A, const float4 B, const float4 C,
                                float& ax, float& ay, float& az) {
    float e1x = B.x - A.x, e1y = B.y - A.y, e1z = B.z - A.z;
    float e2x = C.x - A.x, e2y = C.y - A.y, e2z = C.z - A.z;
    float nx = e1y * e2z - e1z * e2y;
    float ny = e1z * e2x - e1x * e2z;
    float nz = e1x * e2y - e1y * e2x;
    float d  = fmaxf(nx * nx + ny * ny + nz * nz, 1e-24f);
    float r  = fast_rsqrt(d);
    ax += nx * r; ay += ny * r; az += nz * r;
}

__global__ __launch_bounds__(256) void k_all(const float* __restrict__ vrt,
                                             const float* __restrict__ nrm,
                                             const float* __restrict__ ps,
                                             float* __restrict__ out0,
                                             float* __restrict__ out1,
                                             float* __restrict__ out2) {
    __shared__ float4 spv[PS * PS];          // vrt input patch   6.4 KB
    __shared__ float4 spn[PS * PS];          // nrm input patch   6.4 KB
    __shared__ float4 sv4[HS * HS];          // displaced verts  18.5 KB

    int blk    = blockIdx.x;
    int triple = blk / 3;
    int pos    = blk - triple * 3;

    if (pos != 0) {
        // ================= faces path: 12 floats (4 tris) per thread =========
        int t = (triple * 2 + (pos - 1)) * 256 + threadIdx.x;
        if (t >= NFT12) return;
        unsigned ti = 4u * (unsigned)t;
        unsigned s  = ti / (2u * NQ);
        unsigned r1 = ti - s * (2u * NQ);
        unsigned ty = (r1 >= (unsigned)NQ) ? 1u : 0u;
        unsigned qi = r1 - ty * (unsigned)NQ;
        unsigned R  = qi / (NSZ - 1);
        unsigned Q  = qi - R * (NSZ - 1);
        unsigned sbase = s << 18;            // s * 512 * 512
        float v[12];
#pragma unroll
        for (int k = 0; k < 4; ++k) {
            unsigned a = sbase + (R << 9) + Q;
            v[3 * k + 0] = (float)(a + (ty ? 1u : 0u));
            v[3 * k + 1] = (float)(a + (ty ? (unsigned)(NSZ + 1) : 1u));
            v[3 * k + 2] = (float)(a + (unsigned)NSZ);
            // advance to next triangle (carry chain, no divisions)
            Q++;
            if (Q == (unsigned)(NSZ - 1)) {
                Q = 0u; R++;
                if (R == (unsigned)(NSZ - 1)) {
                    R = 0u; ty++;
                    if (ty == 2u) { ty = 0u; sbase += (unsigned)(NSZ * NSZ); }
                }
            }
        }
        float4* o = (float4*)out1 + 3 * t;   // 12t floats -> 48t bytes, 16B aligned
        o[0] = make_float4(v[0], v[1], v[2],  v[3]);
        o[1] = make_float4(v[4], v[5], v[6],  v[7]);
        o[2] = make_float4(v[8], v[9], v[10], v[11]);
        return;
    }

    // ================= vert + normals path ===================================
    int f   = triple >> 8;
    int tl  = triple & 255;
    int tr  = (tl >> 4) * TS;
    int tq  = (tl & 15) * TS;
    int fbm = f * (MSZ * MSZ);
    int fbn = f * (NSZ * NSZ);

    // input patch origin (exact-int lower bound of all float-computed iy0/ix0)
    int iy_base = max(0, ((tr - 1) * (MSZ - 1)) / (NSZ - 1));
    int ix_base = max(0, ((tq - 1) * (MSZ - 1)) / (NSZ - 1));

    // phase 0: stage 20x20 input patch (clamped) into LDS as float4
    for (int p = threadIdx.x; p < PS * PS; p += 256) {
        int r = p / PS, c = p - r * PS;
        int iy = min(iy_base + r, MSZ - 1);
        int ix = min(ix_base + c, MSZ - 1);
        int g  = (fbm + iy * MSZ + ix) * 3;
        spv[p] = make_float4(vrt[g], vrt[g + 1], vrt[g + 2], 0.0f);
        spn[p] = make_float4(nrm[g], nrm[g + 1], nrm[g + 2], 0.0f);
    }
    __syncthreads();

    // phase 1: 34x34 halo of displaced verts -> LDS (+ write interior to out0)
    const float scale = 255.0f / 511.0f;
    for (int p = threadIdx.x; p < HS * HS; p += 256) {
        int pr = p / HS, pq = p - pr * HS;
        int y = tr + pr - 1, x = tq + pq - 1;
        int yc = min(max(y, 0), NSZ - 1);
        int xc = min(max(x, 0), NSZ - 1);

        float cy = (float)yc * scale;
        float cx = (float)xc * scale;
        int iy0 = (int)floorf(cy); iy0 = iy0 < 0 ? 0 : (iy0 > MSZ - 1 ? MSZ - 1 : iy0);
        int ix0 = (int)floorf(cx); ix0 = ix0 < 0 ? 0 : (ix0 > MSZ - 1 ? MSZ - 1 : ix0);
        int iy1 = min(iy0 + 1, MSZ - 1);
        int ix1 = min(ix0 + 1, MSZ - 1);
        float wy = cy - (float)iy0;
        float wx = cx - (float)ix0;
        float w00 = (1.0f - wy) * (1.0f - wx);
        float w01 = (1.0f - wy) * wx;
        float w10 = wy * (1.0f - wx);
        float w11 = wy * wx;

        int l00 = (iy0 - iy_base) * PS + (ix0 - ix_base);
        int l01 = (iy0 - iy_base) * PS + (ix1 - ix_base);
        int l10 = (iy1 - iy_base) * PS + (ix0 - ix_base);
        int l11 = (iy1 - iy_base) * PS + (ix1 - ix_base);

        float4 a00 = spv[l00], a01 = spv[l01], a10 = spv[l10], a11 = spv[l11];
        float4 b00 = spn[l00], b01 = spn[l01], b10 = spn[l10], b11 = spn[l11];

        float vx = a00.x * w00 + a01.x * w01 + a10.x * w10 + a11.x * w11;
        float vy = a00.y * w00 + a01.y * w01 + a10.y * w10 + a11.y * w11;
        float vz = a00.z * w00 + a01.z * w01 + a10.z * w10 + a11.z * w11;
        float nx = b00.x * w00 + b01.x * w01 + b10.x * w10 + b11.x * w11;
        float ny = b00.y * w00 + b01.y * w01 + b10.y * w10 + b11.y * w11;
        float nz = b00.z * w00 + b01.z * w01 + b10.z * w10 + b11.z * w11;

        float mag = __builtin_amdgcn_sqrtf(nx * nx + ny * ny + nz * nz);
        float sig = fast_sigmoid(ps[fbn + yc * NSZ + xc]);
        float add = 0.5f * sig * mag;
        float ox = vx + add, oy = vy + add, oz = vz + add;

        sv4[p] = make_float4(ox, oy, oz, 0.0f);
        if (pr >= 1 && pr <= TS && pq >= 1 && pq <= TS) {
            int gi = (fbn + y * NSZ + x) * 3;
            out0[gi + 0] = ox;
            out0[gi + 1] = oy;
            out0[gi + 2] = oz;
        }
    }
    __syncthreads();

    // phase 2: vertex normals from 6 adjacent tris (unmasked; edge tris are
    // exactly degenerate and contribute 0)
    float sg = (f == 1 || f == 2 || f == 5) ? 1.0f : -1.0f;
    for (int p = threadIdx.x; p < TS * TS; p += 256) {
        int r = p >> 5, q = p & 31;
        int lc = (r + 1) * HS + (q + 1);
        float4 C  = sv4[lc];
        float4 W  = sv4[lc - 1];
        float4 E  = sv4[lc + 1];
        float4 Nn = sv4[lc - HS];
        float4 S  = sv4[lc + HS];
        float4 NE = sv4[lc - HS + 1];
        float4 SW = sv4[lc + HS - 1];

        float ax = 0.0f, ay = 0.0f, az = 0.0f;
        // tri0 of quads (r,q), (r,q-1), (r-1,q)
        tri_acc4(C,  E,  S,  ax, ay, az);
        tri_acc4(W,  C,  SW, ax, ay, az);
        tri_acc4(Nn, NE, C,  ax, ay, az);
        // tri1 of quads (r,q-1), (r-1,q-1), (r-1,q)
        tri_acc4(C,  S,  SW, ax, ay, az);
        tri_acc4(Nn, C,  W,  ax, ay, az);
        tri_acc4(NE, E,  C,  ax, ay, az);

        float d  = fmaxf(ax * ax + ay * ay + az * az, 1e-24f);
        float rs = fast_rsqrt(d) * sg;
        int gi = (fbn + (tr + r) * NSZ + (tq + q)) * 3;
        out2[gi + 0] = ax * rs;
        out2[gi + 1] = ay * rs;
        out2[gi + 2] = az * rs;
    }
}

extern "C" void kernel_launch(void* const* d_in, const int* in_sizes, int n_in,
                              void* d_out, int out_size, void* d_ws, size_t ws_size,
                              hipStream_t stream) {
    const float* vrt = (const float*)d_in[0];
    const float* nrm = (const float*)d_in[1];
    const float* ps  = (const float*)d_in[2];

    float* out0 = (float*)d_out;                 // vert:    6*512*512*3
    float* out1 = out0 + (size_t)NPIX * 3;       // faces:   NFACE*3
    float* out2 = out1 + (size_t)NFACE * 3;      // normals: 6*512*512*3

    k_all<<<GRID, 256, 0, stream>>>(vrt, nrm, ps, out0, out1, out2);
}

// Round 5
// 30.935 us; speedup vs baseline: 1.0432x; 1.0432x over previous
//
#include <hip/hip_runtime.h>
#include <math.h>

#define NSZ 512
#define MSZ 256
#define NPIX (6 * NSZ * NSZ)                      // 1,572,864 vertices
#define NQ   ((NSZ - 1) * (NSZ - 1))              // 261,121 quads per cube face
#define NFACE (6 * 2 * NQ)                        // 3,133,452 triangles
#define F3TOT (NFACE * 3)                         // 9,400,356 floats (divisible by 12)
#define TS 32                                     // output tile
#define HS (TS + 2)                               // vert halo = 34
#define QS (TS + 1)                               // quad halo = 33
#define PS 20                                     // input patch = 20x20 texels
#define NVB (6 * 16 * 16)                         // 1536 vert/normal blocks
#define NFT12 (F3TOT / 12)                        // 783,363 faces threads (12 floats each)
#define GRID (NVB * 3)                            // 4608 blocks: [vert, faces, faces]
#define USZ (2 * QS * QS * 3)                     // union floats = 6534 (>= 3200)

// ---- fast math helpers (raw HW op + 1 Newton step) -----------------------
__device__ inline float fast_rcp(float x) {
    float r = __builtin_amdgcn_rcpf(x);
    return r * (2.0f - x * r);
}
__device__ inline float fast_rsqrt(float d) {
    float r = __builtin_amdgcn_rsqf(d);
    return r * (1.5f - 0.5f * d * r * r);
}
__device__ inline float fast_sigmoid(float x) {
    float e = __builtin_amdgcn_exp2f(-1.442695040888963f * x);
    return fast_rcp(1.0f + e);
}

__global__ __launch_bounds__(256) void k_all(const float* __restrict__ vrt,
                                             const float* __restrict__ nrm,
                                             const float* __restrict__ ps,
                                             float* __restrict__ out0,
                                             float* __restrict__ out1,
                                             float* __restrict__ out2) {
    __shared__ float sv[HS * HS * 3];                 // 13,872 B, live all phases
    __shared__ __align__(16) float smem[USZ];         // 26,136 B, phase-dependent
    float4* spv = (float4*)smem;                      // [PS*PS]   phases 0-1
    float4* spn = ((float4*)smem) + PS * PS;          // [PS*PS]   phases 0-1
    float*  tn0 = smem;                               // [QS*QS*3] phases 1.5-2
    float*  tn1 = smem + QS * QS * 3;                 // [QS*QS*3] phases 1.5-2

    int blk    = blockIdx.x;
    int triple = blk / 3;
    int pos    = blk - triple * 3;

    if (pos != 0) {
        // ========== faces path: 12 floats (4 tris) per thread ==========
        int t = (triple * 2 + (pos - 1)) * 256 + threadIdx.x;
        if (t >= NFT12) return;
        unsigned ti = 4u * (unsigned)t;
        unsigned s  = ti / (2u * NQ);
        unsigned r1 = ti - s * (2u * NQ);
        unsigned ty = (r1 >= (unsigned)NQ) ? 1u : 0u;
        unsigned qi = r1 - ty * (unsigned)NQ;
        unsigned R  = qi / (NSZ - 1);
        unsigned Q  = qi - R * (NSZ - 1);
        unsigned sbase = s << 18;
        float v[12];
#pragma unroll
        for (int k = 0; k < 4; ++k) {
            unsigned a = sbase + (R << 9) + Q;
            v[3 * k + 0] = (float)(a + (ty ? 1u : 0u));
            v[3 * k + 1] = (float)(a + (ty ? (unsigned)(NSZ + 1) : 1u));
            v[3 * k + 2] = (float)(a + (unsigned)NSZ);
            Q++;
            if (Q == (unsigned)(NSZ - 1)) {
                Q = 0u; R++;
                if (R == (unsigned)(NSZ - 1)) {
                    R = 0u; ty++;
                    if (ty == 2u) { ty = 0u; sbase += (unsigned)(NSZ * NSZ); }
                }
            }
        }
        float4* o = (float4*)out1 + 3 * t;
        o[0] = make_float4(v[0], v[1], v[2],  v[3]);
        o[1] = make_float4(v[4], v[5], v[6],  v[7]);
        o[2] = make_float4(v[8], v[9], v[10], v[11]);
        return;
    }

    // ========== vert + normals path ==========
    int f   = triple >> 8;
    int tl  = triple & 255;
    int tr  = (tl >> 4) * TS;
    int tq  = (tl & 15) * TS;
    int fbm = f * (MSZ * MSZ);
    int fbn = f * (NSZ * NSZ);

    // patch origin: exact integer floor of min sampled coordinate
    int iy_base = max(0, ((tr - 1) * (MSZ - 1)) / (NSZ - 1));
    int ix_base = max(0, ((tq - 1) * (MSZ - 1)) / (NSZ - 1));

    // phase 0: stage 20x20 input patch (clamped) into LDS
    for (int p = threadIdx.x; p < PS * PS; p += 256) {
        int r = p / PS, c = p - r * PS;
        int iy = min(iy_base + r, MSZ - 1);
        int ix = min(ix_base + c, MSZ - 1);
        int g  = (fbm + iy * MSZ + ix) * 3;
        spv[p] = make_float4(vrt[g], vrt[g + 1], vrt[g + 2], 0.0f);
        spn[p] = make_float4(nrm[g], nrm[g + 1], nrm[g + 2], 0.0f);
    }
    __syncthreads();

    // phase 1: 34x34 halo of displaced verts -> sv (+ write interior to out0)
    const float scale = 255.0f / 511.0f;
    for (int p = threadIdx.x; p < HS * HS; p += 256) {
        int pr = p / HS, pq = p - pr * HS;
        int y = tr + pr - 1, x = tq + pq - 1;
        int yc = min(max(y, 0), NSZ - 1);
        int xc = min(max(x, 0), NSZ - 1);

        float cy = (float)yc * scale;
        float cx = (float)xc * scale;
        int iy0 = (int)floorf(cy); iy0 = iy0 < 0 ? 0 : (iy0 > MSZ - 1 ? MSZ - 1 : iy0);
        int ix0 = (int)floorf(cx); ix0 = ix0 < 0 ? 0 : (ix0 > MSZ - 1 ? MSZ - 1 : ix0);
        int iy1 = min(iy0 + 1, MSZ - 1);
        int ix1 = min(ix0 + 1, MSZ - 1);
        float wy = cy - (float)iy0;
        float wx = cx - (float)ix0;
        float w00 = (1.0f - wy) * (1.0f - wx);
        float w01 = (1.0f - wy) * wx;
        float w10 = wy * (1.0f - wx);
        float w11 = wy * wx;

        int l00 = (iy0 - iy_base) * PS + (ix0 - ix_base);
        int l01 = (iy0 - iy_base) * PS + (ix1 - ix_base);
        int l10 = (iy1 - iy_base) * PS + (ix0 - ix_base);
        int l11 = (iy1 - iy_base) * PS + (ix1 - ix_base);

        float4 a00 = spv[l00], a01 = spv[l01], a10 = spv[l10], a11 = spv[l11];
        float4 b00 = spn[l00], b01 = spn[l01], b10 = spn[l10], b11 = spn[l11];

        float vx = a00.x * w00 + a01.x * w01 + a10.x * w10 + a11.x * w11;
        float vy = a00.y * w00 + a01.y * w01 + a10.y * w10 + a11.y * w11;
        float vz = a00.z * w00 + a01.z * w01 + a10.z * w10 + a11.z * w11;
        float nx = b00.x * w00 + b01.x * w01 + b10.x * w10 + b11.x * w11;
        float ny = b00.y * w00 + b01.y * w01 + b10.y * w10 + b11.y * w11;
        float nz = b00.z * w00 + b01.z * w01 + b10.z * w10 + b11.z * w11;

        float mag = __builtin_amdgcn_sqrtf(nx * nx + ny * ny + nz * nz);
        float sig = fast_sigmoid(ps[fbn + yc * NSZ + xc]);
        float add = 0.5f * sig * mag;
        float ox = vx + add, oy = vy + add, oz = vz + add;

        sv[p * 3 + 0] = ox;
        sv[p * 3 + 1] = oy;
        sv[p * 3 + 2] = oz;
        if (pr >= 1 && pr <= TS && pq >= 1 && pq <= TS) {
            int gi = (fbn + y * NSZ + x) * 3;
            out0[gi + 0] = ox;
            out0[gi + 1] = oy;
            out0[gi + 2] = oz;
        }
    }
    __syncthreads();

    // phase 1.5: unit normals of the 33x33 quad-halo's 2 tris each, ONCE.
    // (overwrites the input-patch LDS region — patch is dead now)
    for (int p = threadIdx.x; p < QS * QS; p += 256) {
        int Ri = p / QS, Qi = p - Ri * QS;
        bool valid = ((unsigned)(tr + Ri - 1) < (unsigned)(NSZ - 1)) &&
                     ((unsigned)(tq + Qi - 1) < (unsigned)(NSZ - 1));
        float msk = valid ? 1.0f : 0.0f;
        #define SVL(rr, qq, c) sv[(((rr) * HS) + (qq)) * 3 + (c)]
        float ax0 = SVL(Ri,   Qi,   0), ay0 = SVL(Ri,   Qi,   1), az0 = SVL(Ri,   Qi,   2);
        float bx  = SVL(Ri,   Qi+1, 0), by  = SVL(Ri,   Qi+1, 1), bz  = SVL(Ri,   Qi+1, 2);
        float cx  = SVL(Ri+1, Qi,   0), cy  = SVL(Ri+1, Qi,   1), cz  = SVL(Ri+1, Qi,   2);
        float dx  = SVL(Ri+1, Qi+1, 0), dy  = SVL(Ri+1, Qi+1, 1), dz  = SVL(Ri+1, Qi+1, 2);
        #undef SVL

        {   // tri0: (a, b, c)
            float e1x = bx - ax0, e1y = by - ay0, e1z = bz - az0;
            float e2x = cx - ax0, e2y = cy - ay0, e2z = cz - az0;
            float nx = e1y * e2z - e1z * e2y;
            float ny = e1z * e2x - e1x * e2z;
            float nz = e1x * e2y - e1y * e2x;
            float d  = fmaxf(nx * nx + ny * ny + nz * nz, 1e-24f);
            float r  = fast_rsqrt(d) * msk;
            tn0[p * 3 + 0] = nx * r;
            tn0[p * 3 + 1] = ny * r;
            tn0[p * 3 + 2] = nz * r;
        }
        {   // tri1: (b, d, c)
            float e1x = dx - bx, e1y = dy - by, e1z = dz - bz;
            float e2x = cx - bx, e2y = cy - by, e2z = cz - bz;
            float nx = e1y * e2z - e1z * e2y;
            float ny = e1z * e2x - e1x * e2z;
            float nz = e1x * e2y - e1y * e2x;
            float d  = fmaxf(nx * nx + ny * ny + nz * nz, 1e-24f);
            float r  = fast_rsqrt(d) * msk;
            tn1[p * 3 + 0] = nx * r;
            tn1[p * 3 + 1] = ny * r;
            tn1[p * 3 + 2] = nz * r;
        }
    }
    __syncthreads();

    // phase 2: vertex normal = normalize( sum of 6 adjacent tri normals )
    float sg = (f == 1 || f == 2 || f == 5) ? 1.0f : -1.0f;
    for (int p = threadIdx.x; p < TS * TS; p += 256) {
        int r = p >> 5, q = p & 31;
        int q00 = ((r    ) * QS + (q    )) * 3;
        int q01 = ((r    ) * QS + (q + 1)) * 3;
        int q10 = ((r + 1) * QS + (q    )) * 3;
        int q11 = ((r + 1) * QS + (q + 1)) * 3;

        float ax = tn0[q11 + 0] + tn0[q10 + 0] + tn0[q01 + 0]
                 + tn1[q10 + 0] + tn1[q00 + 0] + tn1[q01 + 0];
        float ay = tn0[q11 + 1] + tn0[q10 + 1] + tn0[q01 + 1]
                 + tn1[q10 + 1] + tn1[q00 + 1] + tn1[q01 + 1];
        float az = tn0[q11 + 2] + tn0[q10 + 2] + tn0[q01 + 2]
                 + tn1[q10 + 2] + tn1[q00 + 2] + tn1[q01 + 2];

        float d  = fmaxf(ax * ax + ay * ay + az * az, 1e-24f);
        float rs = fast_rsqrt(d) * sg;
        int gi = (fbn + (tr + r) * NSZ + (tq + q)) * 3;
        out2[gi + 0] = ax * rs;
        out2[gi + 1] = ay * rs;
        out2[gi + 2] = az * rs;
    }
}

extern "C" void kernel_launch(void* const* d_in, const int* in_sizes, int n_in,
                              void* d_out, int out_size, void* d_ws, size_t ws_size,
                              hipStream_t stream) {
    const float* vrt = (const float*)d_in[0];
    const float* nrm = (const float*)d_in[1];
    const float* ps  = (const float*)d_in[2];

    float* out0 = (float*)d_out;                 // vert:    6*512*512*3
    float* out1 = out0 + (size_t)NPIX * 3;       // faces:   NFACE*3
    float* out2 = out1 + (size_t)NFACE * 3;      // normals: 6*512*512*3

    k_all<<<GRID, 256, 0, stream>>>(vrt, nrm, ps, out0, out1, out2);
}